// Round 4
// baseline (272.892 us; speedup 1.0000x reference)
//
#include <hip/hip_runtime.h>
#include <hip/hip_bf16.h>
#include <math.h>

#define HW 3136
#define NC 192
#define NHEADS 6
#define IMG 56
#define NATT 486
#define NATTP 512
#define ATT_SCALE 0.17677669529663687f  // 32^-0.5

typedef __attribute__((ext_vector_type(8))) short short8;
typedef __attribute__((ext_vector_type(8))) unsigned short ushort8;
typedef __attribute__((ext_vector_type(4))) float float4v;

__device__ __forceinline__ float bf2f(unsigned short u) {
    unsigned int x = ((unsigned int)u) << 16;
    return __builtin_bit_cast(float, x);
}
__device__ __forceinline__ unsigned short f2bf(float f) {
    __hip_bfloat16 h = __float2bfloat16(f);
    return __builtin_bit_cast(unsigned short, h);
}
__device__ __forceinline__ void gload_lds16(const void* g, void* l) {
    __builtin_amdgcn_global_load_lds((const __attribute__((address_space(1))) void*)g,
                                     (__attribute__((address_space(3))) void*)l, 16, 0, 0);
}

// x [16][192][3136] fp32 -> xt [50176][192] bf16 (channels-last). grid (784,3), block 256.
__global__ __launch_bounds__(256) void transpose_x(const float* __restrict__ x,
                                                   unsigned short* __restrict__ xt)
{
    __shared__ float tile[64][65];
    int bx = blockIdx.x;
    int n = (bx * 64) / HW;
    int hw0 = (bx * 64) % HW;
    int c0 = blockIdx.y * 64;
    int tl = threadIdx.x & 63, tg = threadIdx.x >> 6;
    const float* xn = x + (size_t)n * NC * HW;
#pragma unroll
    for (int i = 0; i < 16; ++i)
        tile[tg * 16 + i][tl] = xn[(size_t)(c0 + tg * 16 + i) * HW + hw0 + tl];
    __syncthreads();
    unsigned short* xp = xt + ((size_t)n * HW + hw0) * NC + c0;
#pragma unroll
    for (int i = 0; i < 16; ++i) {
        int hwr = tg * 16 + i;
        xp[(size_t)hwr * NC + tl] = f2bf(tile[tl][hwr]);
    }
}

// W [k][d] fp32 -> Wt [d][k] bf16 (Wa padded to 512 rows, zeros). grid 384, block 256.
__global__ __launch_bounds__(256) void prep_weights(
    const float* __restrict__ Wv, const float* __restrict__ Wa, const float* __restrict__ Wp,
    unsigned short* __restrict__ Wvt, unsigned short* __restrict__ Wat,
    unsigned short* __restrict__ Wpt)
{
    int idx = blockIdx.x * 256 + threadIdx.x;   // 192 * 512
    int k = idx >> 9, d = idx & 511;
    if (d < NC) {
        Wvt[(size_t)d * NC + k] = f2bf(Wv[(size_t)k * NC + d]);
        Wpt[(size_t)d * NC + k] = f2bf(Wp[(size_t)k * NC + d]);
    }
    Wat[(size_t)d * NC + k] = (d < NATT) ? f2bf(Wa[(size_t)k * NATT + d]) : (unsigned short)0;
}

// C[m][n] = sum_k A[m][k]*B[n][k], K=192, bf16 in, tile 64x64, 4 waves of 32x32.
// MODE 0: store bf16 C[m*192+n]            (v = xt x Wvt)
// MODE 1: store bf16 C[m*512+n] + bias[n]  (att = xt x Wat, n>=486 pad -> 0)
// MODE 2: store f32 out[img][m][phw] + bias[m], n = global position (out = Wpt x fold)
template<int MODE>
__global__ __launch_bounds__(256) void gemm_mfma(
    const unsigned short* __restrict__ A, const unsigned short* __restrict__ B,
    const float* __restrict__ bias, void* __restrict__ Cout)
{
    __shared__ __align__(16) unsigned short As[64 * 32];
    __shared__ __align__(16) unsigned short Bs[64 * 32];
    int t = threadIdx.x, lane = t & 63, wave = t >> 6;
    int m0 = blockIdx.y * 64, n0 = blockIdx.x * 64;
    int srow = lane >> 2, squad = lane & 3;
    const unsigned short* ga = A + (size_t)(m0 + wave * 16 + srow) * NC + squad * 8;
    const unsigned short* gb = B + (size_t)(n0 + wave * 16 + srow) * NC + squad * 8;
    unsigned short* la = As + wave * 512;
    unsigned short* lb = Bs + wave * 512;
    int fr = lane & 15, fq = lane >> 4;
    int wm = (wave >> 1) * 32, wn = (wave & 1) * 32;
    float4v acc[2][2] = {};

    for (int k0 = 0; k0 < NC; k0 += 32) {
        gload_lds16(ga + k0, la);
        gload_lds16(gb + k0, lb);
        __syncthreads();
        short8 af[2], bfv[2];
#pragma unroll
        for (int mi = 0; mi < 2; ++mi)
            af[mi] = *(const short8*)&As[(wm + mi * 16 + fr) * 32 + fq * 8];
#pragma unroll
        for (int ni = 0; ni < 2; ++ni)
            bfv[ni] = *(const short8*)&Bs[(wn + ni * 16 + fr) * 32 + fq * 8];
#pragma unroll
        for (int mi = 0; mi < 2; ++mi)
#pragma unroll
            for (int ni = 0; ni < 2; ++ni)
                acc[mi][ni] = __builtin_amdgcn_mfma_f32_16x16x32_bf16(
                    af[mi], bfv[ni], acc[mi][ni], 0, 0, 0);
        __syncthreads();
    }

#pragma unroll
    for (int mi = 0; mi < 2; ++mi)
#pragma unroll
        for (int ni = 0; ni < 2; ++ni)
#pragma unroll
            for (int r = 0; r < 4; ++r) {
                int m = m0 + wm + mi * 16 + fq * 4 + r;
                int n = n0 + wn + ni * 16 + fr;
                float val = acc[mi][ni][r];
                if (MODE == 0) {
                    ((unsigned short*)Cout)[(size_t)m * NC + n] = f2bf(val);
                } else if (MODE == 1) {
                    if (n < NATT) val += bias[n];
                    ((unsigned short*)Cout)[(size_t)m * NATTP + n] = f2bf(val);
                } else {
                    int img = n / HW, phw = n - img * HW;
                    ((float*)Cout)[(size_t)img * (NC * HW) + (size_t)m * HW + phw] =
                        val + bias[m];
                }
            }
}

// Fused softmax(l) + fold/unfold weight-combine (25-tap) + aggregation, v2.
// Block = 64 groups (n,hw,head). Phase 1: wave w computes softmax for
// k mod 4 == w, partial 25-tap stencil into LDS. Phase 2: thread =
// (group, quarter) aggregates 8 channels with 16-B v loads.
__global__ __launch_bounds__(256) void fused_att_agg2(
    const unsigned short* __restrict__ att, const unsigned short* __restrict__ v,
    unsigned short* __restrict__ fold)
{
    __shared__ float lwc[4][64][26];
    int t = threadIdx.x;

    // ---- phase 1: partial stencil weights ----
    {
        int wv = t >> 6, ln = t & 63;
        int G = blockIdx.x * 64 + ln;          // (n*HW + hw)*6 + head
        int head = G % NHEADS;
        int rem = G / NHEADS;                  // n*HW + hw
        int hw = rem % HW;
        int h = hw / IMG, w = hw % IMG;
        float pwc[25];
#pragma unroll
        for (int d = 0; d < 25; ++d) pwc[d] = 0.f;
#pragma unroll
        for (int k = 0; k < 9; ++k) {
            if ((k & 3) != wv) continue;       // wave-uniform predicate
            const int oky = k / 3 - 1, okx = k % 3 - 1;
            int hh = h - oky, ww = w - okx;
            if (hh < 0 || hh >= IMG || ww < 0 || ww >= IMG) continue;
            const unsigned short* ap =
                att + (size_t)(rem - oky * IMG - okx) * NATTP + head * 81 + k * 9;
            float a[9];
            float m = -1e30f;
#pragma unroll
            for (int l = 0; l < 9; ++l) {
                a[l] = bf2f(ap[l]);
                m = fmaxf(m, a[l]);
            }
            float s = 0.f;
#pragma unroll
            for (int l = 0; l < 9; ++l) {
                a[l] = __expf((a[l] - m) * ATT_SCALE);
                s += a[l];
            }
            float r = 1.f / s;
#pragma unroll
            for (int l = 0; l < 9; ++l) {
                const int dy = (l / 3 - 1) - oky + 2;
                const int dx = (l % 3 - 1) - okx + 2;
                pwc[dy * 5 + dx] += a[l] * r;
            }
        }
#pragma unroll
        for (int d = 0; d < 25; ++d) lwc[wv][ln][d] = pwc[d];
    }
    __syncthreads();

    // ---- phase 2: aggregate 8 channels per thread ----
    int g = t >> 2, q = t & 3;
    int G = blockIdx.x * 64 + g;
    int head = G % NHEADS;
    int rem = G / NHEADS;
    int hw = rem % HW;
    int h = hw / IMG, w = hw % IMG;

    float wc[25];
#pragma unroll
    for (int d = 0; d < 25; ++d)
        wc[d] = lwc[0][g][d] + lwc[1][g][d] + lwc[2][g][d] + lwc[3][g][d];

    const unsigned short* vb = v + (size_t)rem * NC + head * 32 + q * 8;
    float acc[8];
#pragma unroll
    for (int i = 0; i < 8; ++i) acc[i] = 0.f;
#pragma unroll
    for (int d = 0; d < 25; ++d) {
        const int dy = d / 5 - 2, dx = d % 5 - 2;
        int hh = h + dy, ww = w + dx;
        bool ok = (hh >= 0) & (hh < IMG) & (ww >= 0) & (ww < IMG);
        float wf = ok ? wc[d] : 0.f;
        const unsigned short* vp = vb + (ok ? (dy * IMG + dx) * NC : 0);
        ushort8 vv = *(const ushort8*)vp;
#pragma unroll
        for (int i = 0; i < 8; ++i)
            acc[i] += wf * bf2f(vv[i]);
    }
    unsigned short* fo = fold + (size_t)rem * NC + head * 32 + q * 8;
    ushort8 ov;
#pragma unroll
    for (int i = 0; i < 8; ++i) ov[i] = f2bf(acc[i]);
    *(ushort8*)fo = ov;
}

extern "C" void kernel_launch(void* const* d_in, const int* in_sizes, int n_in,
                              void* d_out, int out_size, void* d_ws, size_t ws_size,
                              hipStream_t stream)
{
    const float* x  = (const float*)d_in[0];
    const float* Wv = (const float*)d_in[1];
    const float* Wa = (const float*)d_in[2];
    const float* ba = (const float*)d_in[3];
    const float* Wp = (const float*)d_in[4];
    const float* bp = (const float*)d_in[5];
    float* out = (float*)d_out;

    unsigned short* xt    = (unsigned short*)d_ws;       // 50176*192
    unsigned short* vbf   = xt + 9633792;                // 50176*192
    unsigned short* attb  = vbf + 9633792;               // 50176*512
    unsigned short* foldb = attb + 25690112;             // 50176*192
    unsigned short* wvt   = foldb + 9633792;             // 192*192
    unsigned short* wat   = wvt + 36864;                 // 512*192
    unsigned short* wpt   = wat + 98304;                 // 192*192

    dim3 blk(256);
    prep_weights<<<384, blk, 0, stream>>>(Wv, Wa, Wp, wvt, wat, wpt);
    transpose_x<<<dim3(784, 3), blk, 0, stream>>>(x, xt);
    gemm_mfma<0><<<dim3(3, 784), blk, 0, stream>>>(xt, wvt, nullptr, vbf);
    gemm_mfma<1><<<dim3(8, 784), blk, 0, stream>>>(xt, wat, ba, attb);
    fused_att_agg2<<<4704, blk, 0, stream>>>(attb, vbf, foldb);
    gemm_mfma<2><<<dim3(784, 3), blk, 0, stream>>>(wpt, foldb, bp, out);
}